// Round 12
// baseline (1328.924 us; speedup 1.0000x reference)
//
#include <hip/hip_runtime.h>
#include <hip/hip_bf16.h>

// ---------------- constants (match reference) ----------------
static constexpr int NA = 50000;   // atoms
static constexpr int NE = 400000;  // edges
static constexpr int HD = 128;     // hidden
static constexpr int NL = 4;       // layers
static constexpr int NM = 500;     // molecules
static constexpr int EPB = 32;     // edges per msg block (NE/EPB = 12500 exact)
static constexpr int HSW = 194;    // u32 stride per LDS h edge-row (192 data + 2 pad)
static constexpr int BCAP = 16384; // capacity of boundary-node list

typedef __hip_bfloat16 bf16;
typedef short short8 __attribute__((ext_vector_type(8)));
typedef float float4v __attribute__((ext_vector_type(4)));
typedef float float2v __attribute__((ext_vector_type(2)));

__device__ __forceinline__ unsigned short f2bf_bits(float x) {
    union { float f; unsigned int u; } c; c.f = x;
    unsigned int lsb = (c.u >> 16) & 1u;
    return (unsigned short)((c.u + 0x7fffu + lsb) >> 16);
}
// pack two f32 -> one u32 of two bf16 (lo, hi). Single HW inst on gfx950.
__device__ __forceinline__ unsigned int pack2bf(float lo, float hi) {
#if defined(__has_builtin) && __has_builtin(__builtin_amdgcn_cvt_pk_bf16_f32)
    auto p = __builtin_amdgcn_cvt_pk_bf16_f32(lo, hi);
    union { decltype(p) v; unsigned int u; } c;
    c.v = p;
    return c.u;
#else
    return (unsigned int)f2bf_bits(lo) | ((unsigned int)f2bf_bits(hi) << 16);
#endif
}
__device__ __forceinline__ float lo16f(unsigned int u) {
    union { unsigned int x; float f; } c; c.x = u << 16; return c.f;
}
__device__ __forceinline__ float hi16f(unsigned int u) {
    union { unsigned int x; float f; } c; c.x = u & 0xffff0000u; return c.f;
}
__device__ __forceinline__ float silu_f(float x) {
    float sg = 1.0f / (1.0f + __expf(-x));
    return x * sg;
}

// ---------------- geometry + degree histogram (fused) ----------------
__global__ void geom_deg_kernel(const float* __restrict__ pos,
                                const int* __restrict__ row, const int* __restrict__ col,
                                float* __restrict__ dist_g, float* __restrict__ dirs,
                                int* __restrict__ deg) {
    int e = blockIdx.x * 256 + threadIdx.x;
    if (e >= NE) return;
    int r = row[e], c = col[e];
    float dx = pos[c*3+0] - pos[r*3+0];
    float dy = pos[c*3+1] - pos[r*3+1];
    float dz = pos[c*3+2] - pos[r*3+2];
    float dist = sqrtf(dx*dx + dy*dy + dz*dz);
    float inv = 1.0f / (dist + 1e-8f);
    dist_g[e] = dist;
    dirs[e*3+0] = dx*inv; dirs[e*3+1] = dy*inv; dirs[e*3+2] = dz*inv;
    atomicAdd(&deg[r], 1);
}

// ---------------- CSR build (multi-block scan) ----------------
__global__ __launch_bounds__(1024) void blockscan_kernel(const int* __restrict__ deg,
                                                         int* __restrict__ incl,
                                                         int* __restrict__ btot) {
    __shared__ int sh[1024];
    int t = threadIdx.x;
    int i = blockIdx.x * 1024 + t;
    int x = (i < NA) ? deg[i] : 0;
    sh[t] = x;
    __syncthreads();
    for (int off = 1; off < 1024; off <<= 1) {
        int v_ = (t >= off) ? sh[t - off] : 0;
        __syncthreads();
        sh[t] += v_;
        __syncthreads();
    }
    if (i < NA) incl[i] = sh[t];
    if (t == 1023) btot[blockIdx.x] = sh[t];
}

__global__ void totals_kernel(int* __restrict__ btot, int nb) {
    if (threadIdx.x == 0 && blockIdx.x == 0) {
        int acc = 0;
        for (int b = 0; b < nb; ++b) { int tv = btot[b]; btot[b] = acc; acc += tv; }
    }
}

// finalize row_ptr/cursor + mark boundary nodes (fused)
__global__ void finalize_kernel(const int* __restrict__ deg, const int* __restrict__ incl,
                                const int* __restrict__ btot,
                                int* __restrict__ row_ptr, int* __restrict__ cursor,
                                int* __restrict__ blist, int* __restrict__ bcount) {
    int i = blockIdx.x * 256 + threadIdx.x;
    if (i >= NA) return;
    int d = deg[i];
    int inc = btot[i >> 10] + incl[i];
    row_ptr[i + 1] = inc;
    cursor[i] = inc - d;
    if (i == 0) row_ptr[0] = 0;
    if (d > 0) {
        int p0 = inc - d, p1 = inc;
        if (p0 / EPB != (p1 - 1) / EPB) {
            int ix = atomicAdd(bcount, 1);
            if (ix < BCAP) blist[ix] = i;
        }
    }
}

__global__ void scatter_kernel(const int* __restrict__ row, int* __restrict__ cursor,
                               int* __restrict__ csr_eid) {
    int e = blockIdx.x * 256 + threadIdx.x;
    if (e >= NE) return;
    int p = atomicAdd(&cursor[row[e]], 1);
    csr_eid[p] = e;
}

// zero m rows of boundary nodes only (interior nodes are '=' written)
__global__ void zero_boundary_kernel(const int* __restrict__ blist,
                                     const int* __restrict__ bcount,
                                     float* __restrict__ m_s, float* __restrict__ m_v) {
    int idx = blockIdx.x * 256 + threadIdx.x;
    int cnt = *bcount; if (cnt > BCAP) cnt = BCAP;
    int ni = idx >> 7, c = idx & 127;
    if (ni >= cnt) return;
    int n = blist[ni];
    m_s[(size_t)n * HD + c] = 0.f;
    size_t vx = (size_t)n * 3 * HD + c;
    m_v[vx] = 0.f; m_v[vx + HD] = 0.f; m_v[vx + 2*HD] = 0.f;
}

// ---------------- node init ----------------
__global__ void embed_kernel(const int* __restrict__ z, const float* __restrict__ emb,
                             float* __restrict__ s, uint4* __restrict__ vp2) {
    int idx = blockIdx.x * 256 + threadIdx.x;
    if (idx >= NA * 64) return;
    int n = idx >> 6, cp = idx & 63;
    float vlo = emb[z[n] * HD + cp];
    float vhi = emb[z[n] * HD + 64 + cp];
    s[(size_t)n * HD + cp] = vlo;
    s[(size_t)n * HD + 64 + cp] = vhi;
    uint4 q;
    q.x = pack2bf(vlo, 0.f);
    q.y = 0u;
    q.z = pack2bf(vhi, 0.f);
    q.w = 0u;
    vp2[idx] = q;
}

// ---------------- generic weight -> B-fragment-linear bf16 ----------------
__global__ void pack_bfrag_kernel(const float* __restrict__ W, int K, int N,
                                  int layers, unsigned short* __restrict__ out) {
    int NT = N >> 4, KC = K >> 5;
    int total = layers * NT * KC * 64;
    int idx = blockIdx.x * 256 + threadIdx.x;
    if (idx >= total) return;
    int lane = idx & 63;
    int kc = (idx >> 6) % KC;
    int nt = ((idx >> 6) / KC) % NT;
    int layer = (idx >> 6) / (KC * NT);
    const float* Wl = W + (size_t)layer * K * N;
    int n = nt * 16 + (lane & 15);
    int k0 = kc * 32 + (lane >> 4) * 8;
    short8 pk;
#pragma unroll
    for (int j = 0; j < 8; ++j)
        pk[j] = (short)f2bf_bits(Wl[(size_t)(k0 + j) * N + n]);
    *(short8*)(&out[(size_t)idx * 8]) = pk;
}

// ---------------- filter W1 (20x128) -> B-frag, K padded to 32 ----------------
__global__ void pack_w1frag_kernel(const float* __restrict__ W1all,
                                   unsigned short* __restrict__ out) {
    int idx = blockIdx.x * 256 + threadIdx.x;   // NL*8*64 = 2048
    if (idx >= NL * 8 * 64) return;
    int lane = idx & 63;
    int nt = (idx >> 6) & 7;
    int layer = idx >> 9;
    const float* W1 = W1all + (size_t)layer * 20 * HD;
    int n = nt * 16 + (lane & 15);
    int k0 = (lane >> 4) * 8;
    short8 pk;
#pragma unroll
    for (int j = 0; j < 8; ++j) {
        int k = k0 + j;
        pk[j] = (k < 20) ? (short)f2bf_bits(W1[(size_t)k * HD + n]) : (short)0;
    }
    *(short8*)(&out[(size_t)idx * 8]) = pk;
}

// ---------------- fused filter(MFMA x2) + aggregate: 32 CSR edges/block -------------
__global__ __launch_bounds__(256, 6) void layer_msg_kernel(
    const float* __restrict__ dist_g, const int* __restrict__ csr_eid,
    const int* __restrict__ row_ptr, const int* __restrict__ row,
    const int* __restrict__ col, const float* __restrict__ dirs,
    const unsigned short* __restrict__ W1frag, const float* __restrict__ b1,
    const unsigned short* __restrict__ W2frag, const float* __restrict__ b2,
    const uint4* __restrict__ vp2,
    float* __restrict__ m_s, float* __restrict__ m_v)
{
    __shared__ __align__(16) unsigned int smem32[EPB * HSW];   // 24832 B
    unsigned short* t_frag = (unsigned short*)smem32;
    __shared__ float dist_s[EPB];
    __shared__ int   col_s[EPB];    // pre-scaled byte offsets (col << 10)
    __shared__ int   rid_s[EPB];
    __shared__ float dirs_s[EPB * 3];

    int tid = threadIdx.x;
    int base = blockIdx.x * EPB;

    if (tid < EPB) {
        int eid = csr_eid[base + tid];
        dist_s[tid] = dist_g[eid];
        col_s[tid] = col[eid] << 10;   // vp2 row = 64 * 16 B = 1024 B
        rid_s[tid] = row[eid];
        dirs_s[tid*3+0] = dirs[eid*3+0];
        dirs_s[tid*3+1] = dirs[eid*3+1];
        dirs_s[tid*3+2] = dirs[eid*3+2];
    }
    __syncthreads();

    int lane = tid & 63, w = tid >> 6;
    int colb = lane & 15, quad = lane >> 4;
    int et = w & 1, ph = w >> 1;

    // ---- phase 1: GEMM1 via MFMA (wave: edge-half et, channel-half ph) ----
    {
        float d = dist_s[et * 16 + colb];
        short8 arbf;
#pragma unroll
        for (int j = 0; j < 8; ++j) {
            int k = quad * 8 + j;
            float t = d - (5.0f / 19.0f) * (float)k;
            // k >= 20 multiplies zero rows of padded W1 -> value irrelevant, skip exp
            arbf[j] = (k < 20) ? (short)f2bf_bits(__expf(-t * t)) : (short)0;
        }
        float4v acc1[4];
#pragma unroll
        for (int nt2 = 0; nt2 < 4; ++nt2) {
            short8 b = *(const short8*)(W1frag + ((size_t)((ph * 4 + nt2) * 64 + lane)) * 8);
            float4v z = {0.f, 0.f, 0.f, 0.f};
            acc1[nt2] = __builtin_amdgcn_mfma_f32_16x16x32_bf16(arbf, b, z, 0, 0, 0);
        }
#pragma unroll
        for (int nt2 = 0; nt2 < 4; ++nt2) {
            int n1 = (ph * 4 + nt2) * 16 + colb;
            float bias = b1[n1];
            int kc2 = n1 >> 5, kq = (n1 >> 3) & 3, j2 = n1 & 7;
#pragma unroll
            for (int r = 0; r < 4; ++r) {
                float val = silu_f(acc1[nt2][r] + bias);
                int em = quad * 4 + r;
                t_frag[(((et * 4 + kc2) * 64) + kq * 16 + em) * 8 + j2] = f2bf_bits(val);
            }
        }
    }
    __syncthreads();

    // ---- phase 2: load own A-frags (single edge half per wave — no spill) ----
    short8 a[4];
#pragma unroll
    for (int kc = 0; kc < 4; ++kc)
        a[kc] = *(const short8*)(&t_frag[((et * 4 + kc) * 64 + lane) * 8]);
    __syncthreads();   // frag reads done -> smem becomes h

    // ---- phase 3: MFMA GEMM2 over 6 tile-pairs (t, t+4); packed u32 h-writes ----
#pragma unroll
    for (int i = 0; i < 6; ++i) {
        int p = ph * 6 + i;
        int t = ((p >> 2) << 3) + (p & 3);
        int n_lo = t * 16 + colb;
        int seg = n_lo >> 7, cp0 = n_lo & 63;
        float biasL = b2[n_lo], biasH = b2[n_lo + 64];
        float4v accL = {0.f,0.f,0.f,0.f}, accH = {0.f,0.f,0.f,0.f};
#pragma unroll
        for (int kc = 0; kc < 4; ++kc) {
            short8 bL = *(const short8*)(W2frag + ((size_t)((t    ) * 4 + kc) * 64 + lane) * 8);
            short8 bH = *(const short8*)(W2frag + ((size_t)((t + 4) * 4 + kc) * 64 + lane) * 8);
            accL = __builtin_amdgcn_mfma_f32_16x16x32_bf16(a[kc], bL, accL, 0, 0, 0);
            accH = __builtin_amdgcn_mfma_f32_16x16x32_bf16(a[kc], bH, accH, 0, 0, 0);
        }
        int e0 = et * 16 + quad * 4;
        unsigned int* hp = smem32 + e0 * HSW + seg * 64 + cp0;
#pragma unroll
        for (int r = 0; r < 4; ++r)
            hp[r * HSW] = pack2bf(accL[r] + biasL, accH[r] + biasH);
    }
    __syncthreads();

    // ---- phase 4: aggregation, 4 wave-teams x 64 channel-pairs, float2 packed ----
    int cp = tid & 63, team = tid >> 6;
    int cpo = cp << 4;
    const char* vp2b = (const char*)vp2;
    const unsigned int* h32 = smem32;
    int node_lo = rid_s[0], node_hi = rid_s[EPB - 1];
    for (int n = node_lo + team; n <= node_hi; n += 4) {
        int p0 = row_ptr[n], p1 = row_ptr[n + 1];
        int lo = p0 - base; if (lo < 0) lo = 0;
        int hi = p1 - base; if (hi > EPB) hi = EPB;
        if (lo >= hi) continue;
        bool interior = (p0 >= base) && (p1 <= base + EPB);
        float2v as2 = {0.f, 0.f}, a02 = {0.f, 0.f}, a12 = {0.f, 0.f}, a22 = {0.f, 0.f};
        int e = lo;
        for (; e + 2 <= hi; e += 2) {
            uint4 qa = *(const uint4*)(vp2b + (size_t)(unsigned)(col_s[e] + cpo));
            uint4 qb = *(const uint4*)(vp2b + (size_t)(unsigned)(col_s[e + 1] + cpo));
#pragma unroll
            for (int j = 0; j < 2; ++j) {
                uint4 q = j ? qb : qa;
                int ee = e + j;
                unsigned int hx0 = h32[ee * HSW + cp];
                unsigned int hx1 = h32[ee * HSW + 64 + cp];
                unsigned int hx2 = h32[ee * HSW + 128 + cp];
                float2v sc2;  sc2.x = lo16f(q.x);   sc2.y = lo16f(q.z);
                float2v v02;  v02.x = hi16f(q.x);   v02.y = hi16f(q.z);
                float2v v12;  v12.x = lo16f(q.y);   v12.y = lo16f(q.w);
                float2v v22;  v22.x = hi16f(q.y);   v22.y = hi16f(q.w);
                float2v pss2; pss2.x = lo16f(hx0);  pss2.y = hi16f(hx0);
                float2v pvv2; pvv2.x = lo16f(hx1);  pvv2.y = hi16f(hx1);
                float2v psv2; psv2.x = lo16f(hx2);  psv2.y = hi16f(hx2);
                float2v svd2 = psv2 * sc2;
                as2 += pss2 * sc2;
                float d0 = dirs_s[ee*3], d1 = dirs_s[ee*3+1], d2 = dirs_s[ee*3+2];
                a02 += pvv2 * v02 + svd2 * d0;
                a12 += pvv2 * v12 + svd2 * d1;
                a22 += pvv2 * v22 + svd2 * d2;
            }
        }
        for (; e < hi; ++e) {
            uint4 q = *(const uint4*)(vp2b + (size_t)(unsigned)(col_s[e] + cpo));
            unsigned int hx0 = h32[e * HSW + cp];
            unsigned int hx1 = h32[e * HSW + 64 + cp];
            unsigned int hx2 = h32[e * HSW + 128 + cp];
            float2v sc2;  sc2.x = lo16f(q.x);   sc2.y = lo16f(q.z);
            float2v v02;  v02.x = hi16f(q.x);   v02.y = hi16f(q.z);
            float2v v12;  v12.x = lo16f(q.y);   v12.y = lo16f(q.w);
            float2v v22;  v22.x = hi16f(q.y);   v22.y = hi16f(q.w);
            float2v pss2; pss2.x = lo16f(hx0);  pss2.y = hi16f(hx0);
            float2v pvv2; pvv2.x = lo16f(hx1);  pvv2.y = hi16f(hx1);
            float2v psv2; psv2.x = lo16f(hx2);  psv2.y = hi16f(hx2);
            float2v svd2 = psv2 * sc2;
            as2 += pss2 * sc2;
            float d0 = dirs_s[e*3], d1 = dirs_s[e*3+1], d2 = dirs_s[e*3+2];
            a02 += pvv2 * v02 + svd2 * d0;
            a12 += pvv2 * v12 + svd2 * d1;
            a22 += pvv2 * v22 + svd2 * d2;
        }
        size_t msx = (size_t)n * HD;
        size_t mvx = (size_t)n * 3 * HD;
        if (interior) {
            m_s[msx + cp] = as2.x;          m_s[msx + 64 + cp] = as2.y;
            m_v[mvx + cp] = a02.x;          m_v[mvx + 64 + cp] = a02.y;
            m_v[mvx + HD + cp] = a12.x;     m_v[mvx + HD + 64 + cp] = a12.y;
            m_v[mvx + 2*HD + cp] = a22.x;   m_v[mvx + 2*HD + 64 + cp] = a22.y;
        } else {
            atomicAdd(&m_s[msx + cp], as2.x);          atomicAdd(&m_s[msx + 64 + cp], as2.y);
            atomicAdd(&m_v[mvx + cp], a02.x);          atomicAdd(&m_v[mvx + 64 + cp], a02.y);
            atomicAdd(&m_v[mvx + HD + cp], a12.x);     atomicAdd(&m_v[mvx + HD + 64 + cp], a12.y);
            atomicAdd(&m_v[mvx + 2*HD + cp], a22.x);   atomicAdd(&m_v[mvx + 2*HD + 64 + cp], a22.y);
        }
    }
}

// ---------------- fused update MLP (MFMA x2) + s/v apply -------------
__global__ __launch_bounds__(256) void upd12_kernel(
    float* __restrict__ s, uint4* __restrict__ vp2,
    const float* __restrict__ m_s, const float* __restrict__ m_v,
    const unsigned short* __restrict__ W1frag, const float* __restrict__ b1,
    const unsigned short* __restrict__ W2frag, const float* __restrict__ b2)
{
    __shared__ __align__(16) unsigned short afrag[64 * 384];
    int tid = threadIdx.x;
    int r0 = blockIdx.x * 64;

    // staging: r = tid>>2 (64 rows), sub = tid&3, kg = sub*12 + t  (no div/mod)
    {
        int r = tid >> 2, sub = tid & 3;
        int rr = r0 + r; if (rr >= NA) rr = NA - 1;
        const float* srow = s + (size_t)rr * HD;
        const float* msr = m_s + (size_t)rr * HD;
        const float* mvr = m_v + (size_t)rr * 3 * HD;
        int m = r & 15, rt = r >> 4;
#pragma unroll
        for (int t = 0; t < 12; ++t) {
            int kg = sub * 12 + t;
            float vals[8];
            if (kg < 16) {
                const float* p = srow + kg * 8;
#pragma unroll
                for (int j = 0; j < 8; ++j) vals[j] = p[j];
            } else if (kg < 32) {
                const float* p = msr + (kg - 16) * 8;
#pragma unroll
                for (int j = 0; j < 8; ++j) vals[j] = p[j];
            } else {
                int cb = (kg - 32) * 8;
                const float* p = mvr + cb;
#pragma unroll
                for (int j = 0; j < 8; ++j) {
                    float x = p[j], y = p[HD + j], z = p[2*HD + j];
                    vals[j] = sqrtf(x*x + y*y + z*z);
                }
            }
            int kc = kg >> 2, hi = kg & 3;
            short8 pk;
#pragma unroll
            for (int j = 0; j < 8; ++j) pk[j] = (short)f2bf_bits(vals[j]);
            *(short8*)(&afrag[(((rt * 12 + kc) * 64) + hi * 16 + m) * 8]) = pk;
        }
    }
    __syncthreads();

    int lane = tid & 63, w = tid >> 6;
    int colb = lane & 15, quad = lane >> 4;

    float4v acc1[8];
#pragma unroll
    for (int nt = 0; nt < 8; ++nt) acc1[nt] = (float4v){0.f,0.f,0.f,0.f};
    for (int kc = 0; kc < 12; ++kc) {
        short8 a = *(const short8*)(&afrag[((w * 12 + kc) * 64 + lane) * 8]);
#pragma unroll
        for (int nt = 0; nt < 8; ++nt) {
            short8 b = *(const short8*)(W1frag + ((size_t)(nt * 12 + kc) * 64 + lane) * 8);
            acc1[nt] = __builtin_amdgcn_mfma_f32_16x16x32_bf16(a, b, acc1[nt], 0, 0, 0);
        }
    }
    __syncthreads();

#pragma unroll
    for (int nt = 0; nt < 8; ++nt) {
        int n1 = nt * 16 + colb;
        int kc2 = n1 >> 5, hi2 = (n1 >> 3) & 3, j2 = n1 & 7;
#pragma unroll
        for (int r = 0; r < 4; ++r) {
            float t1v = silu_f(acc1[nt][r] + b1[n1]);
            int m2 = quad * 4 + r;
            afrag[(((w * 4 + kc2) * 64) + hi2 * 16 + m2) * 8 + j2] = f2bf_bits(t1v);
        }
    }
    __syncthreads();

    short8 a2[4];
#pragma unroll
    for (int kc = 0; kc < 4; ++kc)
        a2[kc] = *(const short8*)(&afrag[((w * 4 + kc) * 64 + lane) * 8]);

    for (int i = 0; i < 4; ++i) {
        float4v dl = {0.f,0.f,0.f,0.f}, dh = {0.f,0.f,0.f,0.f};
        float4v al = {0.f,0.f,0.f,0.f}, ah = {0.f,0.f,0.f,0.f};
        float4v bl = {0.f,0.f,0.f,0.f}, bh = {0.f,0.f,0.f,0.f};
#pragma unroll
        for (int kc = 0; kc < 4; ++kc) {
            short8 w_dl = *(const short8*)(W2frag + ((size_t)((i     ) * 4 + kc) * 64 + lane) * 8);
            short8 w_dh = *(const short8*)(W2frag + ((size_t)((i +  4) * 4 + kc) * 64 + lane) * 8);
            short8 w_al = *(const short8*)(W2frag + ((size_t)((i +  8) * 4 + kc) * 64 + lane) * 8);
            short8 w_ah = *(const short8*)(W2frag + ((size_t)((i + 12) * 4 + kc) * 64 + lane) * 8);
            short8 w_bl = *(const short8*)(W2frag + ((size_t)((i + 16) * 4 + kc) * 64 + lane) * 8);
            short8 w_bh = *(const short8*)(W2frag + ((size_t)((i + 20) * 4 + kc) * 64 + lane) * 8);
            dl = __builtin_amdgcn_mfma_f32_16x16x32_bf16(a2[kc], w_dl, dl, 0, 0, 0);
            dh = __builtin_amdgcn_mfma_f32_16x16x32_bf16(a2[kc], w_dh, dh, 0, 0, 0);
            al = __builtin_amdgcn_mfma_f32_16x16x32_bf16(a2[kc], w_al, al, 0, 0, 0);
            ah = __builtin_amdgcn_mfma_f32_16x16x32_bf16(a2[kc], w_ah, ah, 0, 0, 0);
            bl = __builtin_amdgcn_mfma_f32_16x16x32_bf16(a2[kc], w_bl, bl, 0, 0, 0);
            bh = __builtin_amdgcn_mfma_f32_16x16x32_bf16(a2[kc], w_bh, bh, 0, 0, 0);
        }
        int cp = i * 16 + colb;
        float bd_l = b2[cp],        bd_h = b2[64 + cp];
        float ba_l = b2[128 + cp],  ba_h = b2[192 + cp];
        float bb_l = b2[256 + cp],  bb_h = b2[320 + cp];
#pragma unroll
        for (int r = 0; r < 4; ++r) {
            int rr = r0 + 16 * w + quad * 4 + r;
            if (rr < NA) {
                size_t sx = (size_t)rr * HD;
                size_t vx = (size_t)rr * 3 * HD;
                float news_l = s[sx + cp]      + dl[r] + bd_l;
                float news_h = s[sx + 64 + cp] + dh[r] + bd_h;
                s[sx + cp] = news_l;
                s[sx + 64 + cp] = news_h;
                float alv_l = al[r] + ba_l, alv_h = ah[r] + ba_h;
                float bev_l = bl[r] + bb_l, bev_h = bh[r] + bb_h;
                uint4 q = vp2[(size_t)rr * 64 + cp];
                float nv0_l = alv_l * hi16f(q.x) + bev_l * m_v[vx + cp];
                float nv1_l = alv_l * lo16f(q.y) + bev_l * m_v[vx + HD + cp];
                float nv2_l = alv_l * hi16f(q.y) + bev_l * m_v[vx + 2*HD + cp];
                float nv0_h = alv_h * hi16f(q.z) + bev_h * m_v[vx + 64 + cp];
                float nv1_h = alv_h * lo16f(q.w) + bev_h * m_v[vx + HD + 64 + cp];
                float nv2_h = alv_h * hi16f(q.w) + bev_h * m_v[vx + 2*HD + 64 + cp];
                uint4 nq;
                nq.x = pack2bf(news_l, nv0_l);
                nq.y = pack2bf(nv1_l, nv2_l);
                nq.z = pack2bf(news_h, nv0_h);
                nq.w = pack2bf(nv1_h, nv2_h);
                vp2[(size_t)rr * 64 + cp] = nq;
            }
        }
    }
}

// ---------------- readout ----------------
__global__ __launch_bounds__(128) void readout_kernel(
    const float* __restrict__ s, const int* __restrict__ batch,
    const float* __restrict__ lamW1, const float* __restrict__ lamb1,
    const float* __restrict__ lamW2, const float* __restrict__ lamb2,
    const float* __restrict__ phiW1, const float* __restrict__ phib1,
    const float* __restrict__ phiW2, const float* __restrict__ phib2,
    float* __restrict__ out)
{
    __shared__ int seg[2];
    __shared__ float hms[HD];
    __shared__ float red[HD];
    int m = blockIdx.x, c = threadIdx.x;
    if (c < 2) {
        int target = m + c;
        int lo = 0, hi = NA;
        while (lo < hi) { int mid = (lo + hi) >> 1; if (batch[mid] < target) lo = mid + 1; else hi = mid; }
        seg[c] = lo;
    }
    __syncthreads();
    int st = seg[0], en = seg[1];
    float acc = 0.f;
    for (int n2 = st; n2 < en; ++n2) acc += s[(size_t)n2 * HD + c];
    float hm = acc / (float)(en - st);
    hms[c] = hm;
    __syncthreads();

    float t = lamb1[c];
    for (int k = 0; k < HD; ++k) t += hms[k] * lamW1[k * HD + c];
    t = silu_f(t);
    red[c] = t * lamW2[c];
    __syncthreads();
    for (int off = 64; off > 0; off >>= 1) { if (c < off) red[c] += red[c + off]; __syncthreads(); }
    if (c == 0) out[m] = red[0] + lamb2[0];
    __syncthreads();

    t = phib1[c];
    for (int k = 0; k < HD; ++k) t += hms[k] * phiW1[k * HD + c];
    t = silu_f(t);
    red[c] = t * phiW2[c];
    __syncthreads();
    for (int off = 64; off > 0; off >>= 1) { if (c < off) red[c] += red[c + off]; __syncthreads(); }
    if (c == 0) { float x = red[0] + phib2[0]; out[NM + m] = 1.0f / (1.0f + __expf(-x)); }
}

// ---------------- host ----------------
extern "C" void kernel_launch(void* const* d_in, const int* in_sizes, int n_in,
                              void* d_out, int out_size, void* d_ws, size_t ws_size,
                              hipStream_t stream) {
    (void)in_sizes; (void)n_in; (void)out_size; (void)ws_size;
    const int*   z          = (const int*)  d_in[0];
    const float* pos        = (const float*)d_in[1];
    const int*   edge_index = (const int*)  d_in[2];
    const int*   batch      = (const int*)  d_in[3];
    const float* emb        = (const float*)d_in[4];
    const float* filt_W1    = (const float*)d_in[5];
    const float* filt_b1    = (const float*)d_in[6];
    const float* filt_W2    = (const float*)d_in[7];
    const float* filt_b2    = (const float*)d_in[8];
    const float* upd_W1     = (const float*)d_in[9];
    const float* upd_b1     = (const float*)d_in[10];
    const float* upd_W2     = (const float*)d_in[11];
    const float* upd_b2     = (const float*)d_in[12];
    const float* lam_W1     = (const float*)d_in[13];
    const float* lam_b1     = (const float*)d_in[14];
    const float* lam_W2     = (const float*)d_in[15];
    const float* lam_b2     = (const float*)d_in[16];
    const float* phi_W1     = (const float*)d_in[17];
    const float* phi_b1     = (const float*)d_in[18];
    const float* phi_W2     = (const float*)d_in[19];
    const float* phi_b2     = (const float*)d_in[20];
    float* out = (float*)d_out;

    const int* row = edge_index;
    const int* col = edge_index + NE;

    char* ws = (char*)d_ws;
    size_t off = 0;
    auto alloc = [&](size_t bytes) -> char* {
        char* p = ws + off;
        off = (off + bytes + 255) & ~(size_t)255;
        return p;
    };
    float* dist_g  = (float*)alloc((size_t)NE * 4);
    float* dirs    = (float*)alloc((size_t)NE * 3 * 4);
    int*   csr_eid = (int*)  alloc((size_t)NE * 4);
    int*   row_ptr = (int*)  alloc((size_t)(NA + 1) * 4);
    int*   deg     = (int*)  alloc((size_t)NA * 4);
    int*   cursor  = (int*)  alloc((size_t)NA * 4);
    int*   incl    = (int*)  alloc((size_t)NA * 4);
    int*   btot    = (int*)  alloc(256);
    int*   blist   = (int*)  alloc((size_t)BCAP * 4);
    int*   bcount  = (int*)  alloc(256);
    float* s       = (float*)alloc((size_t)NA * HD * 4);
    uint4* vp2     = (uint4*)alloc((size_t)NA * 64 * 16);
    float* m_s     = (float*)alloc((size_t)NA * HD * 4);
    float* m_v     = (float*)alloc((size_t)NA * HD * 3 * 4);
    unsigned short* fW1frag = (unsigned short*)alloc((size_t)NL * 8 * 64 * 8 * 2);
    unsigned short* fW2frag = (unsigned short*)alloc((size_t)NL * 24 * 4 * 64 * 8 * 2);
    unsigned short* uW1frag = (unsigned short*)alloc((size_t)NL * 8 * 12 * 64 * 8 * 2);
    unsigned short* uW2frag = (unsigned short*)alloc((size_t)NL * 24 * 4 * 64 * 8 * 2);

    const int EB = (NE + 255) / 256;
    const int SCAN_BLOCKS = (NA + 1023) / 1024;  // 49
    const int MSG_BLOCKS = NE / EPB;             // 12500 (exact)
    const int UPD_BLOCKS = (NA + 63) / 64;       // 782
    const int ZB_BLOCKS = (BCAP * 128) / 256;

    hipMemsetAsync(deg, 0, (size_t)NA * 4, stream);
    hipMemsetAsync(bcount, 0, 4, stream);
    geom_deg_kernel<<<EB, 256, 0, stream>>>(pos, row, col, dist_g, dirs, deg);
    blockscan_kernel<<<SCAN_BLOCKS, 1024, 0, stream>>>(deg, incl, btot);
    totals_kernel<<<1, 64, 0, stream>>>(btot, SCAN_BLOCKS);
    finalize_kernel<<<(NA + 255) / 256, 256, 0, stream>>>(deg, incl, btot, row_ptr, cursor,
                                                          blist, bcount);
    scatter_kernel<<<EB, 256, 0, stream>>>(row, cursor, csr_eid);
    embed_kernel<<<(NA * 64 + 255) / 256, 256, 0, stream>>>(z, emb, s, vp2);
    pack_w1frag_kernel<<<8, 256, 0, stream>>>(filt_W1, fW1frag);
    pack_bfrag_kernel<<<96, 256, 0, stream>>>(filt_W2, 128, 384, NL, fW2frag);
    pack_bfrag_kernel<<<96, 256, 0, stream>>>(upd_W1, 384, 128, NL, uW1frag);
    pack_bfrag_kernel<<<96, 256, 0, stream>>>(upd_W2, 128, 384, NL, uW2frag);

    for (int i = 0; i < NL; ++i) {
        const float* fb1 = filt_b1 + (size_t)i * HD;
        const float* fb2 = filt_b2 + (size_t)i * 384;
        const unsigned short* fW1f = fW1frag + (size_t)i * 8 * 64 * 8;
        const unsigned short* fW2f = fW2frag + (size_t)i * 24 * 4 * 64 * 8;
        const unsigned short* uW1f = uW1frag + (size_t)i * 8 * 12 * 64 * 8;
        const unsigned short* uW2f = uW2frag + (size_t)i * 24 * 4 * 64 * 8;
        const float* ub1 = upd_b1 + (size_t)i * HD;
        const float* ub2 = upd_b2 + (size_t)i * 384;

        zero_boundary_kernel<<<ZB_BLOCKS, 256, 0, stream>>>(blist, bcount, m_s, m_v);
        layer_msg_kernel<<<MSG_BLOCKS, 256, 0, stream>>>(
            dist_g, csr_eid, row_ptr, row, col, dirs,
            fW1f, fb1, fW2f, fb2, vp2, m_s, m_v);
        upd12_kernel<<<UPD_BLOCKS, 256, 0, stream>>>(
            s, vp2, m_s, m_v, uW1f, ub1, uW2f, ub2);
    }

    readout_kernel<<<NM, 128, 0, stream>>>(s, batch,
        lam_W1, lam_b1, lam_W2, lam_b2,
        phi_W1, phi_b1, phi_W2, phi_b2, out);
}

// Round 13
// 1223.466 us; speedup vs baseline: 1.0862x; 1.0862x over previous
//
#include <hip/hip_runtime.h>
#include <hip/hip_bf16.h>

// ---------------- constants (match reference) ----------------
static constexpr int NA = 50000;   // atoms
static constexpr int NE = 400000;  // edges
static constexpr int HD = 128;     // hidden
static constexpr int NL = 4;       // layers
static constexpr int NM = 500;     // molecules
static constexpr int EPB = 32;     // edges per msg block (NE/EPB = 12500 exact)
static constexpr int HSW = 194;    // u32 stride per LDS h edge-row (192 data + 2 pad)
static constexpr int BCAP = 16384; // capacity of boundary-node list

typedef __hip_bfloat16 bf16;
typedef short short8 __attribute__((ext_vector_type(8)));
typedef float float4v __attribute__((ext_vector_type(4)));
typedef float float2v __attribute__((ext_vector_type(2)));

__device__ __forceinline__ unsigned short f2bf_bits(float x) {
    union { float f; unsigned int u; } c; c.f = x;
    unsigned int lsb = (c.u >> 16) & 1u;
    return (unsigned short)((c.u + 0x7fffu + lsb) >> 16);
}
// pack two f32 -> one u32 of two bf16 (lo, hi). Single HW inst on gfx950.
__device__ __forceinline__ unsigned int pack2bf(float lo, float hi) {
#if defined(__has_builtin) && __has_builtin(__builtin_amdgcn_cvt_pk_bf16_f32)
    auto p = __builtin_amdgcn_cvt_pk_bf16_f32(lo, hi);
    union { decltype(p) v; unsigned int u; } c;
    c.v = p;
    return c.u;
#else
    return (unsigned int)f2bf_bits(lo) | ((unsigned int)f2bf_bits(hi) << 16);
#endif
}
__device__ __forceinline__ float lo16f(unsigned int u) {
    union { unsigned int x; float f; } c; c.x = u << 16; return c.f;
}
__device__ __forceinline__ float hi16f(unsigned int u) {
    union { unsigned int x; float f; } c; c.x = u & 0xffff0000u; return c.f;
}
__device__ __forceinline__ float silu_f(float x) {
    float sg = 1.0f / (1.0f + __expf(-x));
    return x * sg;
}

// ---------------- geometry + degree histogram (fused) ----------------
__global__ void geom_deg_kernel(const float* __restrict__ pos,
                                const int* __restrict__ row, const int* __restrict__ col,
                                float* __restrict__ dist_g, float* __restrict__ dirs,
                                int* __restrict__ deg) {
    int e = blockIdx.x * 256 + threadIdx.x;
    if (e >= NE) return;
    int r = row[e], c = col[e];
    float dx = pos[c*3+0] - pos[r*3+0];
    float dy = pos[c*3+1] - pos[r*3+1];
    float dz = pos[c*3+2] - pos[r*3+2];
    float dist = sqrtf(dx*dx + dy*dy + dz*dz);
    float inv = 1.0f / (dist + 1e-8f);
    dist_g[e] = dist;
    dirs[e*3+0] = dx*inv; dirs[e*3+1] = dy*inv; dirs[e*3+2] = dz*inv;
    atomicAdd(&deg[r], 1);
}

// ---------------- CSR build (multi-block scan) ----------------
__global__ __launch_bounds__(1024) void blockscan_kernel(const int* __restrict__ deg,
                                                         int* __restrict__ incl,
                                                         int* __restrict__ btot) {
    __shared__ int sh[1024];
    int t = threadIdx.x;
    int i = blockIdx.x * 1024 + t;
    int x = (i < NA) ? deg[i] : 0;
    sh[t] = x;
    __syncthreads();
    for (int off = 1; off < 1024; off <<= 1) {
        int v_ = (t >= off) ? sh[t - off] : 0;
        __syncthreads();
        sh[t] += v_;
        __syncthreads();
    }
    if (i < NA) incl[i] = sh[t];
    if (t == 1023) btot[blockIdx.x] = sh[t];
}

__global__ void totals_kernel(int* __restrict__ btot, int nb) {
    if (threadIdx.x == 0 && blockIdx.x == 0) {
        int acc = 0;
        for (int b = 0; b < nb; ++b) { int tv = btot[b]; btot[b] = acc; acc += tv; }
    }
}

// finalize row_ptr/cursor + mark boundary nodes (fused)
__global__ void finalize_kernel(const int* __restrict__ deg, const int* __restrict__ incl,
                                const int* __restrict__ btot,
                                int* __restrict__ row_ptr, int* __restrict__ cursor,
                                int* __restrict__ blist, int* __restrict__ bcount) {
    int i = blockIdx.x * 256 + threadIdx.x;
    if (i >= NA) return;
    int d = deg[i];
    int inc = btot[i >> 10] + incl[i];
    row_ptr[i + 1] = inc;
    cursor[i] = inc - d;
    if (i == 0) row_ptr[0] = 0;
    if (d > 0) {
        int p0 = inc - d, p1 = inc;
        if (p0 / EPB != (p1 - 1) / EPB) {
            int ix = atomicAdd(bcount, 1);
            if (ix < BCAP) blist[ix] = i;
        }
    }
}

__global__ void scatter_kernel(const int* __restrict__ row, int* __restrict__ cursor,
                               int* __restrict__ csr_eid) {
    int e = blockIdx.x * 256 + threadIdx.x;
    if (e >= NE) return;
    int p = atomicAdd(&cursor[row[e]], 1);
    csr_eid[p] = e;
}

// zero m rows of boundary nodes only (interior nodes are '=' written)
__global__ void zero_boundary_kernel(const int* __restrict__ blist,
                                     const int* __restrict__ bcount,
                                     float* __restrict__ m_s, float* __restrict__ m_v) {
    int idx = blockIdx.x * 256 + threadIdx.x;
    int cnt = *bcount; if (cnt > BCAP) cnt = BCAP;
    int ni = idx >> 7, c = idx & 127;
    if (ni >= cnt) return;
    int n = blist[ni];
    m_s[(size_t)n * HD + c] = 0.f;
    size_t vx = (size_t)n * 3 * HD + c;
    m_v[vx] = 0.f; m_v[vx + HD] = 0.f; m_v[vx + 2*HD] = 0.f;
}

// ---------------- node init ----------------
__global__ void embed_kernel(const int* __restrict__ z, const float* __restrict__ emb,
                             float* __restrict__ s, uint4* __restrict__ vp2) {
    int idx = blockIdx.x * 256 + threadIdx.x;
    if (idx >= NA * 64) return;
    int n = idx >> 6, cp = idx & 63;
    float vlo = emb[z[n] * HD + cp];
    float vhi = emb[z[n] * HD + 64 + cp];
    s[(size_t)n * HD + cp] = vlo;
    s[(size_t)n * HD + 64 + cp] = vhi;
    uint4 q;
    q.x = pack2bf(vlo, 0.f);
    q.y = 0u;
    q.z = pack2bf(vhi, 0.f);
    q.w = 0u;
    vp2[idx] = q;
}

// ---------------- generic weight -> B-fragment-linear bf16 ----------------
__global__ void pack_bfrag_kernel(const float* __restrict__ W, int K, int N,
                                  int layers, unsigned short* __restrict__ out) {
    int NT = N >> 4, KC = K >> 5;
    int total = layers * NT * KC * 64;
    int idx = blockIdx.x * 256 + threadIdx.x;
    if (idx >= total) return;
    int lane = idx & 63;
    int kc = (idx >> 6) % KC;
    int nt = ((idx >> 6) / KC) % NT;
    int layer = (idx >> 6) / (KC * NT);
    const float* Wl = W + (size_t)layer * K * N;
    int n = nt * 16 + (lane & 15);
    int k0 = kc * 32 + (lane >> 4) * 8;
    short8 pk;
#pragma unroll
    for (int j = 0; j < 8; ++j)
        pk[j] = (short)f2bf_bits(Wl[(size_t)(k0 + j) * N + n]);
    *(short8*)(&out[(size_t)idx * 8]) = pk;
}

// ---------------- filter W1 (20x128) -> B-frag, K padded to 32 ----------------
__global__ void pack_w1frag_kernel(const float* __restrict__ W1all,
                                   unsigned short* __restrict__ out) {
    int idx = blockIdx.x * 256 + threadIdx.x;   // NL*8*64 = 2048
    if (idx >= NL * 8 * 64) return;
    int lane = idx & 63;
    int nt = (idx >> 6) & 7;
    int layer = idx >> 9;
    const float* W1 = W1all + (size_t)layer * 20 * HD;
    int n = nt * 16 + (lane & 15);
    int k0 = (lane >> 4) * 8;
    short8 pk;
#pragma unroll
    for (int j = 0; j < 8; ++j) {
        int k = k0 + j;
        pk[j] = (k < 20) ? (short)f2bf_bits(W1[(size_t)k * HD + n]) : (short)0;
    }
    *(short8*)(&out[(size_t)idx * 8]) = pk;
}

// ---------------- fused filter(MFMA x2) + aggregate: 32 CSR edges/block -------------
__global__ __launch_bounds__(256, 6) void layer_msg_kernel(
    const float* __restrict__ dist_g, const int* __restrict__ csr_eid,
    const int* __restrict__ row_ptr, const int* __restrict__ row,
    const int* __restrict__ col, const float* __restrict__ dirs,
    const unsigned short* __restrict__ W1frag, const float* __restrict__ b1,
    const unsigned short* __restrict__ W2frag, const float* __restrict__ b2,
    const uint4* __restrict__ vp2,
    float* __restrict__ m_s, float* __restrict__ m_v)
{
    __shared__ __align__(16) unsigned int smem32[EPB * HSW];   // 24832 B
    unsigned short* t_frag = (unsigned short*)smem32;
    __shared__ float dist_s[EPB];
    __shared__ int   col_s[EPB];    // pre-scaled byte offsets (col << 10)
    __shared__ int   rid_s[EPB];
    __shared__ float dirs_s[EPB * 3];

    int tid = threadIdx.x;
    int base = blockIdx.x * EPB;

    if (tid < EPB) {
        int eid = csr_eid[base + tid];
        dist_s[tid] = dist_g[eid];
        col_s[tid] = col[eid] << 10;   // vp2 row = 64 * 16 B = 1024 B
        rid_s[tid] = row[eid];
        dirs_s[tid*3+0] = dirs[eid*3+0];
        dirs_s[tid*3+1] = dirs[eid*3+1];
        dirs_s[tid*3+2] = dirs[eid*3+2];
    }
    __syncthreads();

    int lane = tid & 63, w = tid >> 6;
    int colb = lane & 15, quad = lane >> 4;
    int et = w & 1, ph = w >> 1;

    // ---- phase 1: GEMM1 via MFMA (wave: edge-half et, channel-half ph) ----
    {
        float d = dist_s[et * 16 + colb];
        short8 arbf;
#pragma unroll
        for (int j = 0; j < 8; ++j) {
            int k = quad * 8 + j;
            float t = d - (5.0f / 19.0f) * (float)k;
            // k >= 20 multiplies zero rows of padded W1 -> value irrelevant, skip exp
            arbf[j] = (k < 20) ? (short)f2bf_bits(__expf(-t * t)) : (short)0;
        }
        float4v acc1[4];
#pragma unroll
        for (int nt2 = 0; nt2 < 4; ++nt2) {
            short8 b = *(const short8*)(W1frag + ((size_t)((ph * 4 + nt2) * 64 + lane)) * 8);
            float4v z = {0.f, 0.f, 0.f, 0.f};
            acc1[nt2] = __builtin_amdgcn_mfma_f32_16x16x32_bf16(arbf, b, z, 0, 0, 0);
        }
#pragma unroll
        for (int nt2 = 0; nt2 < 4; ++nt2) {
            int n1 = (ph * 4 + nt2) * 16 + colb;
            float bias = b1[n1];
            int kc2 = n1 >> 5, kq = (n1 >> 3) & 3, j2 = n1 & 7;
#pragma unroll
            for (int r = 0; r < 4; ++r) {
                float val = silu_f(acc1[nt2][r] + bias);
                int em = quad * 4 + r;
                t_frag[(((et * 4 + kc2) * 64) + kq * 16 + em) * 8 + j2] = f2bf_bits(val);
            }
        }
    }
    __syncthreads();

    // ---- phase 2: load own A-frags (single edge half per wave — no spill) ----
    short8 a[4];
#pragma unroll
    for (int kc = 0; kc < 4; ++kc)
        a[kc] = *(const short8*)(&t_frag[((et * 4 + kc) * 64 + lane) * 8]);
    __syncthreads();   // frag reads done -> smem becomes h

    // ---- phase 3: MFMA GEMM2 over 6 tile-pairs (t, t+4); packed u32 h-writes ----
#pragma unroll
    for (int i = 0; i < 6; ++i) {
        int p = ph * 6 + i;
        int t = ((p >> 2) << 3) + (p & 3);
        int n_lo = t * 16 + colb;
        int seg = n_lo >> 7, cp0 = n_lo & 63;
        float biasL = b2[n_lo], biasH = b2[n_lo + 64];
        float4v accL = {0.f,0.f,0.f,0.f}, accH = {0.f,0.f,0.f,0.f};
#pragma unroll
        for (int kc = 0; kc < 4; ++kc) {
            short8 bL = *(const short8*)(W2frag + ((size_t)((t    ) * 4 + kc) * 64 + lane) * 8);
            short8 bH = *(const short8*)(W2frag + ((size_t)((t + 4) * 4 + kc) * 64 + lane) * 8);
            accL = __builtin_amdgcn_mfma_f32_16x16x32_bf16(a[kc], bL, accL, 0, 0, 0);
            accH = __builtin_amdgcn_mfma_f32_16x16x32_bf16(a[kc], bH, accH, 0, 0, 0);
        }
        int e0 = et * 16 + quad * 4;
        unsigned int* hp = smem32 + e0 * HSW + seg * 64 + cp0;
#pragma unroll
        for (int r = 0; r < 4; ++r)
            hp[r * HSW] = pack2bf(accL[r] + biasL, accH[r] + biasH);
    }
    __syncthreads();

    // ---- phase 4: aggregation, 4 wave-teams x 64 channel-pairs, float2 packed ----
    int cp = tid & 63, team = tid >> 6;
    int cpo = cp << 4;
    const char* vp2b = (const char*)vp2;
    const unsigned int* h32 = smem32;
    int node_lo = rid_s[0], node_hi = rid_s[EPB - 1];
    for (int n = node_lo + team; n <= node_hi; n += 4) {
        int p0 = row_ptr[n], p1 = row_ptr[n + 1];
        int lo = p0 - base; if (lo < 0) lo = 0;
        int hi = p1 - base; if (hi > EPB) hi = EPB;
        if (lo >= hi) continue;
        bool interior = (p0 >= base) && (p1 <= base + EPB);
        float2v as2 = {0.f, 0.f}, a02 = {0.f, 0.f}, a12 = {0.f, 0.f}, a22 = {0.f, 0.f};
        int e = lo;
        for (; e + 2 <= hi; e += 2) {
            uint4 qa = *(const uint4*)(vp2b + (size_t)(unsigned)(col_s[e] + cpo));
            uint4 qb = *(const uint4*)(vp2b + (size_t)(unsigned)(col_s[e + 1] + cpo));
#pragma unroll
            for (int j = 0; j < 2; ++j) {
                uint4 q = j ? qb : qa;
                int ee = e + j;
                unsigned int hx0 = h32[ee * HSW + cp];
                unsigned int hx1 = h32[ee * HSW + 64 + cp];
                unsigned int hx2 = h32[ee * HSW + 128 + cp];
                float2v sc2;  sc2.x = lo16f(q.x);   sc2.y = lo16f(q.z);
                float2v v02;  v02.x = hi16f(q.x);   v02.y = hi16f(q.z);
                float2v v12;  v12.x = lo16f(q.y);   v12.y = lo16f(q.w);
                float2v v22;  v22.x = hi16f(q.y);   v22.y = hi16f(q.w);
                float2v pss2; pss2.x = lo16f(hx0);  pss2.y = hi16f(hx0);
                float2v pvv2; pvv2.x = lo16f(hx1);  pvv2.y = hi16f(hx1);
                float2v psv2; psv2.x = lo16f(hx2);  psv2.y = hi16f(hx2);
                float2v svd2 = psv2 * sc2;
                as2 += pss2 * sc2;
                float d0 = dirs_s[ee*3], d1 = dirs_s[ee*3+1], d2 = dirs_s[ee*3+2];
                a02 += pvv2 * v02 + svd2 * d0;
                a12 += pvv2 * v12 + svd2 * d1;
                a22 += pvv2 * v22 + svd2 * d2;
            }
        }
        for (; e < hi; ++e) {
            uint4 q = *(const uint4*)(vp2b + (size_t)(unsigned)(col_s[e] + cpo));
            unsigned int hx0 = h32[e * HSW + cp];
            unsigned int hx1 = h32[e * HSW + 64 + cp];
            unsigned int hx2 = h32[e * HSW + 128 + cp];
            float2v sc2;  sc2.x = lo16f(q.x);   sc2.y = lo16f(q.z);
            float2v v02;  v02.x = hi16f(q.x);   v02.y = hi16f(q.z);
            float2v v12;  v12.x = lo16f(q.y);   v12.y = lo16f(q.w);
            float2v v22;  v22.x = hi16f(q.y);   v22.y = hi16f(q.w);
            float2v pss2; pss2.x = lo16f(hx0);  pss2.y = hi16f(hx0);
            float2v pvv2; pvv2.x = lo16f(hx1);  pvv2.y = hi16f(hx1);
            float2v psv2; psv2.x = lo16f(hx2);  psv2.y = hi16f(hx2);
            float2v svd2 = psv2 * sc2;
            as2 += pss2 * sc2;
            float d0 = dirs_s[e*3], d1 = dirs_s[e*3+1], d2 = dirs_s[e*3+2];
            a02 += pvv2 * v02 + svd2 * d0;
            a12 += pvv2 * v12 + svd2 * d1;
            a22 += pvv2 * v22 + svd2 * d2;
        }
        size_t msx = (size_t)n * HD;
        size_t mvx = (size_t)n * 3 * HD;
        if (interior) {
            m_s[msx + cp] = as2.x;          m_s[msx + 64 + cp] = as2.y;
            m_v[mvx + cp] = a02.x;          m_v[mvx + 64 + cp] = a02.y;
            m_v[mvx + HD + cp] = a12.x;     m_v[mvx + HD + 64 + cp] = a12.y;
            m_v[mvx + 2*HD + cp] = a22.x;   m_v[mvx + 2*HD + 64 + cp] = a22.y;
        } else {
            atomicAdd(&m_s[msx + cp], as2.x);          atomicAdd(&m_s[msx + 64 + cp], as2.y);
            atomicAdd(&m_v[mvx + cp], a02.x);          atomicAdd(&m_v[mvx + 64 + cp], a02.y);
            atomicAdd(&m_v[mvx + HD + cp], a12.x);     atomicAdd(&m_v[mvx + HD + 64 + cp], a12.y);
            atomicAdd(&m_v[mvx + 2*HD + cp], a22.x);   atomicAdd(&m_v[mvx + 2*HD + 64 + cp], a22.y);
        }
    }
}

// ---------------- fused update MLP (MFMA x2) + s/v apply -------------
__global__ __launch_bounds__(256) void upd12_kernel(
    float* __restrict__ s, uint4* __restrict__ vp2,
    const float* __restrict__ m_s, const float* __restrict__ m_v,
    const unsigned short* __restrict__ W1frag, const float* __restrict__ b1,
    const unsigned short* __restrict__ W2frag, const float* __restrict__ b2)
{
    __shared__ __align__(16) unsigned short afrag[64 * 384];
    int tid = threadIdx.x;
    int r0 = blockIdx.x * 64;

    // staging: R10 pattern — consecutive lanes cover consecutive kg (coalesced loads)
#pragma unroll
    for (int t = 0; t < 12; ++t) {
        int id = tid + 256 * t;
        int r = id / 48;
        int kg = id % 48;
        int rr = r0 + r; if (rr >= NA) rr = NA - 1;
        float vals[8];
        if (kg < 16) {
            const float* p = s + (size_t)rr * HD + kg * 8;
#pragma unroll
            for (int j = 0; j < 8; ++j) vals[j] = p[j];
        } else if (kg < 32) {
            const float* p = m_s + (size_t)rr * HD + (kg - 16) * 8;
#pragma unroll
            for (int j = 0; j < 8; ++j) vals[j] = p[j];
        } else {
            int cb = (kg - 32) * 8;
            const float* p = m_v + (size_t)rr * 3 * HD + cb;
#pragma unroll
            for (int j = 0; j < 8; ++j) {
                float x = p[j], y = p[HD + j], z = p[2*HD + j];
                vals[j] = sqrtf(x*x + y*y + z*z);
            }
        }
        int kc = kg >> 2, hi = kg & 3, m = r & 15, rt = r >> 4;
        short8 pk;
#pragma unroll
        for (int j = 0; j < 8; ++j) pk[j] = (short)f2bf_bits(vals[j]);
        *(short8*)(&afrag[(((rt * 12 + kc) * 64) + hi * 16 + m) * 8]) = pk;
    }
    __syncthreads();

    int lane = tid & 63, w = tid >> 6;
    int colb = lane & 15, quad = lane >> 4;

    float4v acc1[8];
#pragma unroll
    for (int nt = 0; nt < 8; ++nt) acc1[nt] = (float4v){0.f,0.f,0.f,0.f};
    for (int kc = 0; kc < 12; ++kc) {
        short8 a = *(const short8*)(&afrag[((w * 12 + kc) * 64 + lane) * 8]);
#pragma unroll
        for (int nt = 0; nt < 8; ++nt) {
            short8 b = *(const short8*)(W1frag + ((size_t)(nt * 12 + kc) * 64 + lane) * 8);
            acc1[nt] = __builtin_amdgcn_mfma_f32_16x16x32_bf16(a, b, acc1[nt], 0, 0, 0);
        }
    }
    __syncthreads();

#pragma unroll
    for (int nt = 0; nt < 8; ++nt) {
        int n1 = nt * 16 + colb;
        int kc2 = n1 >> 5, hi2 = (n1 >> 3) & 3, j2 = n1 & 7;
#pragma unroll
        for (int r = 0; r < 4; ++r) {
            float t1v = silu_f(acc1[nt][r] + b1[n1]);
            int m2 = quad * 4 + r;
            afrag[(((w * 4 + kc2) * 64) + hi2 * 16 + m2) * 8 + j2] = f2bf_bits(t1v);
        }
    }
    __syncthreads();

    short8 a2[4];
#pragma unroll
    for (int kc = 0; kc < 4; ++kc)
        a2[kc] = *(const short8*)(&afrag[((w * 4 + kc) * 64 + lane) * 8]);

    for (int i = 0; i < 4; ++i) {
        float4v dl = {0.f,0.f,0.f,0.f}, dh = {0.f,0.f,0.f,0.f};
        float4v al = {0.f,0.f,0.f,0.f}, ah = {0.f,0.f,0.f,0.f};
        float4v bl = {0.f,0.f,0.f,0.f}, bh = {0.f,0.f,0.f,0.f};
#pragma unroll
        for (int kc = 0; kc < 4; ++kc) {
            short8 w_dl = *(const short8*)(W2frag + ((size_t)((i     ) * 4 + kc) * 64 + lane) * 8);
            short8 w_dh = *(const short8*)(W2frag + ((size_t)((i +  4) * 4 + kc) * 64 + lane) * 8);
            short8 w_al = *(const short8*)(W2frag + ((size_t)((i +  8) * 4 + kc) * 64 + lane) * 8);
            short8 w_ah = *(const short8*)(W2frag + ((size_t)((i + 12) * 4 + kc) * 64 + lane) * 8);
            short8 w_bl = *(const short8*)(W2frag + ((size_t)((i + 16) * 4 + kc) * 64 + lane) * 8);
            short8 w_bh = *(const short8*)(W2frag + ((size_t)((i + 20) * 4 + kc) * 64 + lane) * 8);
            dl = __builtin_amdgcn_mfma_f32_16x16x32_bf16(a2[kc], w_dl, dl, 0, 0, 0);
            dh = __builtin_amdgcn_mfma_f32_16x16x32_bf16(a2[kc], w_dh, dh, 0, 0, 0);
            al = __builtin_amdgcn_mfma_f32_16x16x32_bf16(a2[kc], w_al, al, 0, 0, 0);
            ah = __builtin_amdgcn_mfma_f32_16x16x32_bf16(a2[kc], w_ah, ah, 0, 0, 0);
            bl = __builtin_amdgcn_mfma_f32_16x16x32_bf16(a2[kc], w_bl, bl, 0, 0, 0);
            bh = __builtin_amdgcn_mfma_f32_16x16x32_bf16(a2[kc], w_bh, bh, 0, 0, 0);
        }
        int cp = i * 16 + colb;
        float bd_l = b2[cp],        bd_h = b2[64 + cp];
        float ba_l = b2[128 + cp],  ba_h = b2[192 + cp];
        float bb_l = b2[256 + cp],  bb_h = b2[320 + cp];
#pragma unroll
        for (int r = 0; r < 4; ++r) {
            int rr = r0 + 16 * w + quad * 4 + r;
            if (rr < NA) {
                size_t sx = (size_t)rr * HD;
                size_t vx = (size_t)rr * 3 * HD;
                float news_l = s[sx + cp]      + dl[r] + bd_l;
                float news_h = s[sx + 64 + cp] + dh[r] + bd_h;
                s[sx + cp] = news_l;
                s[sx + 64 + cp] = news_h;
                float alv_l = al[r] + ba_l, alv_h = ah[r] + ba_h;
                float bev_l = bl[r] + bb_l, bev_h = bh[r] + bb_h;
                uint4 q = vp2[(size_t)rr * 64 + cp];
                float nv0_l = alv_l * hi16f(q.x) + bev_l * m_v[vx + cp];
                float nv1_l = alv_l * lo16f(q.y) + bev_l * m_v[vx + HD + cp];
                float nv2_l = alv_l * hi16f(q.y) + bev_l * m_v[vx + 2*HD + cp];
                float nv0_h = alv_h * hi16f(q.z) + bev_h * m_v[vx + 64 + cp];
                float nv1_h = alv_h * lo16f(q.w) + bev_h * m_v[vx + HD + 64 + cp];
                float nv2_h = alv_h * hi16f(q.w) + bev_h * m_v[vx + 2*HD + 64 + cp];
                uint4 nq;
                nq.x = pack2bf(news_l, nv0_l);
                nq.y = pack2bf(nv1_l, nv2_l);
                nq.z = pack2bf(news_h, nv0_h);
                nq.w = pack2bf(nv1_h, nv2_h);
                vp2[(size_t)rr * 64 + cp] = nq;
            }
        }
    }
}

// ---------------- readout ----------------
__global__ __launch_bounds__(128) void readout_kernel(
    const float* __restrict__ s, const int* __restrict__ batch,
    const float* __restrict__ lamW1, const float* __restrict__ lamb1,
    const float* __restrict__ lamW2, const float* __restrict__ lamb2,
    const float* __restrict__ phiW1, const float* __restrict__ phib1,
    const float* __restrict__ phiW2, const float* __restrict__ phib2,
    float* __restrict__ out)
{
    __shared__ int seg[2];
    __shared__ float hms[HD];
    __shared__ float red[HD];
    int m = blockIdx.x, c = threadIdx.x;
    if (c < 2) {
        int target = m + c;
        int lo = 0, hi = NA;
        while (lo < hi) { int mid = (lo + hi) >> 1; if (batch[mid] < target) lo = mid + 1; else hi = mid; }
        seg[c] = lo;
    }
    __syncthreads();
    int st = seg[0], en = seg[1];
    float acc = 0.f;
    for (int n2 = st; n2 < en; ++n2) acc += s[(size_t)n2 * HD + c];
    float hm = acc / (float)(en - st);
    hms[c] = hm;
    __syncthreads();

    float t = lamb1[c];
    for (int k = 0; k < HD; ++k) t += hms[k] * lamW1[k * HD + c];
    t = silu_f(t);
    red[c] = t * lamW2[c];
    __syncthreads();
    for (int off = 64; off > 0; off >>= 1) { if (c < off) red[c] += red[c + off]; __syncthreads(); }
    if (c == 0) out[m] = red[0] + lamb2[0];
    __syncthreads();

    t = phib1[c];
    for (int k = 0; k < HD; ++k) t += hms[k] * phiW1[k * HD + c];
    t = silu_f(t);
    red[c] = t * phiW2[c];
    __syncthreads();
    for (int off = 64; off > 0; off >>= 1) { if (c < off) red[c] += red[c + off]; __syncthreads(); }
    if (c == 0) { float x = red[0] + phib2[0]; out[NM + m] = 1.0f / (1.0f + __expf(-x)); }
}

// ---------------- host ----------------
extern "C" void kernel_launch(void* const* d_in, const int* in_sizes, int n_in,
                              void* d_out, int out_size, void* d_ws, size_t ws_size,
                              hipStream_t stream) {
    (void)in_sizes; (void)n_in; (void)out_size; (void)ws_size;
    const int*   z          = (const int*)  d_in[0];
    const float* pos        = (const float*)d_in[1];
    const int*   edge_index = (const int*)  d_in[2];
    const int*   batch      = (const int*)  d_in[3];
    const float* emb        = (const float*)d_in[4];
    const float* filt_W1    = (const float*)d_in[5];
    const float* filt_b1    = (const float*)d_in[6];
    const float* filt_W2    = (const float*)d_in[7];
    const float* filt_b2    = (const float*)d_in[8];
    const float* upd_W1     = (const float*)d_in[9];
    const float* upd_b1     = (const float*)d_in[10];
    const float* upd_W2     = (const float*)d_in[11];
    const float* upd_b2     = (const float*)d_in[12];
    const float* lam_W1     = (const float*)d_in[13];
    const float* lam_b1     = (const float*)d_in[14];
    const float* lam_W2     = (const float*)d_in[15];
    const float* lam_b2     = (const float*)d_in[16];
    const float* phi_W1     = (const float*)d_in[17];
    const float* phi_b1     = (const float*)d_in[18];
    const float* phi_W2     = (const float*)d_in[19];
    const float* phi_b2     = (const float*)d_in[20];
    float* out = (float*)d_out;

    const int* row = edge_index;
    const int* col = edge_index + NE;

    char* ws = (char*)d_ws;
    size_t off = 0;
    auto alloc = [&](size_t bytes) -> char* {
        char* p = ws + off;
        off = (off + bytes + 255) & ~(size_t)255;
        return p;
    };
    float* dist_g  = (float*)alloc((size_t)NE * 4);
    float* dirs    = (float*)alloc((size_t)NE * 3 * 4);
    int*   csr_eid = (int*)  alloc((size_t)NE * 4);
    int*   row_ptr = (int*)  alloc((size_t)(NA + 1) * 4);
    int*   deg     = (int*)  alloc((size_t)NA * 4);
    int*   cursor  = (int*)  alloc((size_t)NA * 4);
    int*   incl    = (int*)  alloc((size_t)NA * 4);
    int*   btot    = (int*)  alloc(256);
    int*   blist   = (int*)  alloc((size_t)BCAP * 4);
    int*   bcount  = (int*)  alloc(256);
    float* s       = (float*)alloc((size_t)NA * HD * 4);
    uint4* vp2     = (uint4*)alloc((size_t)NA * 64 * 16);
    float* m_s     = (float*)alloc((size_t)NA * HD * 4);
    float* m_v     = (float*)alloc((size_t)NA * HD * 3 * 4);
    unsigned short* fW1frag = (unsigned short*)alloc((size_t)NL * 8 * 64 * 8 * 2);
    unsigned short* fW2frag = (unsigned short*)alloc((size_t)NL * 24 * 4 * 64 * 8 * 2);
    unsigned short* uW1frag = (unsigned short*)alloc((size_t)NL * 8 * 12 * 64 * 8 * 2);
    unsigned short* uW2frag = (unsigned short*)alloc((size_t)NL * 24 * 4 * 64 * 8 * 2);

    const int EB = (NE + 255) / 256;
    const int SCAN_BLOCKS = (NA + 1023) / 1024;  // 49
    const int MSG_BLOCKS = NE / EPB;             // 12500 (exact)
    const int UPD_BLOCKS = (NA + 63) / 64;       // 782
    const int ZB_BLOCKS = (BCAP * 128) / 256;

    hipMemsetAsync(deg, 0, (size_t)NA * 4, stream);
    hipMemsetAsync(bcount, 0, 4, stream);
    geom_deg_kernel<<<EB, 256, 0, stream>>>(pos, row, col, dist_g, dirs, deg);
    blockscan_kernel<<<SCAN_BLOCKS, 1024, 0, stream>>>(deg, incl, btot);
    totals_kernel<<<1, 64, 0, stream>>>(btot, SCAN_BLOCKS);
    finalize_kernel<<<(NA + 255) / 256, 256, 0, stream>>>(deg, incl, btot, row_ptr, cursor,
                                                          blist, bcount);
    scatter_kernel<<<EB, 256, 0, stream>>>(row, cursor, csr_eid);
    embed_kernel<<<(NA * 64 + 255) / 256, 256, 0, stream>>>(z, emb, s, vp2);
    pack_w1frag_kernel<<<8, 256, 0, stream>>>(filt_W1, fW1frag);
    pack_bfrag_kernel<<<96, 256, 0, stream>>>(filt_W2, 128, 384, NL, fW2frag);
    pack_bfrag_kernel<<<96, 256, 0, stream>>>(upd_W1, 384, 128, NL, uW1frag);
    pack_bfrag_kernel<<<96, 256, 0, stream>>>(upd_W2, 128, 384, NL, uW2frag);

    for (int i = 0; i < NL; ++i) {
        const float* fb1 = filt_b1 + (size_t)i * HD;
        const float* fb2 = filt_b2 + (size_t)i * 384;
        const unsigned short* fW1f = fW1frag + (size_t)i * 8 * 64 * 8;
        const unsigned short* fW2f = fW2frag + (size_t)i * 24 * 4 * 64 * 8;
        const unsigned short* uW1f = uW1frag + (size_t)i * 8 * 12 * 64 * 8;
        const unsigned short* uW2f = uW2frag + (size_t)i * 24 * 4 * 64 * 8;
        const float* ub1 = upd_b1 + (size_t)i * HD;
        const float* ub2 = upd_b2 + (size_t)i * 384;

        zero_boundary_kernel<<<ZB_BLOCKS, 256, 0, stream>>>(blist, bcount, m_s, m_v);
        layer_msg_kernel<<<MSG_BLOCKS, 256, 0, stream>>>(
            dist_g, csr_eid, row_ptr, row, col, dirs,
            fW1f, fb1, fW2f, fb2, vp2, m_s, m_v);
        upd12_kernel<<<UPD_BLOCKS, 256, 0, stream>>>(
            s, vp2, m_s, m_v, uW1f, ub1, uW2f, ub2);
    }

    readout_kernel<<<NM, 128, 0, stream>>>(s, batch,
        lam_W1, lam_b1, lam_W2, lam_b2,
        phi_W1, phi_b1, phi_W2, phi_b2, out);
}